// Round 3
// baseline (24.770 us; speedup 1.0000x reference)
//
#include <hip/hip_runtime.h>

#define HH 512
#define WW 512
#define XG 128   // col groups  (WW/4)
#define YG 128   // row groups  (HH/4)

__global__ __launch_bounds__(256) void median3_kernel(const float* __restrict__ x,
                                                      float* __restrict__ out,
                                                      int nimg) {
    int tid = blockIdx.x * blockDim.x + threadIdx.x;
    int xg  = tid & (XG - 1);           // 4-col group
    int yg  = (tid >> 7) & (YG - 1);    // 4-row group
    int img = tid >> 14;
    if (img >= nimg) return;

    int lane = threadIdx.x & 63;
    int y0 = yg << 2;
    int c0 = xg << 2;
    const float* p = x + (size_t)img * HH * WW;

    // 6 rows (y0-1 .. y0+4) x 6 cols (c0-1 .. c0+4), zero-padded at borders.
    // Horizontal halo comes from neighbor lanes via shuffle; only lane 0/63
    // of each wave (wave boundary) do a scalar load.
    float c[6][6];
#pragma unroll
    for (int dr = 0; dr < 6; ++dr) {
        int r = y0 + dr - 1;
        float4 m = make_float4(0.f, 0.f, 0.f, 0.f);
        float l = 0.f, rr = 0.f;
        if (r >= 0 && r < HH) {          // wave-uniform (yg constant per wave)
            const float* row = p + (size_t)r * WW + c0;
            m = *reinterpret_cast<const float4*>(row);
            l  = __shfl_up(m.w, 1);
            rr = __shfl_down(m.x, 1);
            if (lane == 0)  l  = (xg > 0)      ? row[-1] : 0.f;
            if (lane == 63) rr = (xg < XG - 1) ? row[4]  : 0.f;
        }
        c[dr][0] = l;
        c[dr][1] = m.x; c[dr][2] = m.y; c[dr][3] = m.z; c[dr][4] = m.w;
        c[dr][5] = rr;
    }

    float* outp = out + (size_t)img * HH * WW + (size_t)y0 * WW + c0;
#pragma unroll
    for (int t = 0; t < 4; ++t) {
        // sort each of the 6 columns of the 3-row window (t..t+2)
        float lo[6], mi[6], hi[6];
#pragma unroll
        for (int j = 0; j < 6; ++j) {
            float a = c[t][j], b = c[t + 1][j], d = c[t + 2][j];
            lo[j] = fminf(fminf(a, b), d);
            hi[j] = fmaxf(fmaxf(a, b), d);
            mi[j] = __builtin_amdgcn_fmed3f(a, b, d);
        }
        // Smith: median9 = med3(max3(lows), med3(mids), min3(highs))
        float4 o;
        float* op = &o.x;
#pragma unroll
        for (int j = 0; j < 4; ++j) {
            float mx = fmaxf(fmaxf(lo[j], lo[j + 1]), lo[j + 2]);
            float md = __builtin_amdgcn_fmed3f(mi[j], mi[j + 1], mi[j + 2]);
            float mn = fminf(fminf(hi[j], hi[j + 1]), hi[j + 2]);
            op[j] = __builtin_amdgcn_fmed3f(mx, md, mn);
        }
        *reinterpret_cast<float4*>(outp + (size_t)t * WW) = o;
    }
}

extern "C" void kernel_launch(void* const* d_in, const int* in_sizes, int n_in,
                              void* d_out, int out_size, void* d_ws, size_t ws_size,
                              hipStream_t stream) {
    const float* x = (const float*)d_in[0];
    float* out = (float*)d_out;
    int nimg = in_sizes[0] / (HH * WW);          // 16 * 3 = 48
    int total_threads = nimg * YG * XG;          // one thread per 4x4 output tile
    int block = 256;
    int grid = (total_threads + block - 1) / block;
    median3_kernel<<<grid, block, 0, stream>>>(x, out, nimg);
}

// Round 4
// 24.668 us; speedup vs baseline: 1.0041x; 1.0041x over previous
//
#include <hip/hip_runtime.h>

#define HH 512
#define WW 512
#define XG 128   // col groups  (WW/4)
#define YG 128   // row groups  (HH/4)

__global__ __launch_bounds__(256) void median3_kernel(const float* __restrict__ x,
                                                      float* __restrict__ out,
                                                      int nimg) {
    int tid = blockIdx.x * blockDim.x + threadIdx.x;
    int xg  = tid & (XG - 1);           // 4-col group
    int yg  = (tid >> 7) & (YG - 1);    // 4-row group
    int img = tid >> 14;
    if (img >= nimg) return;

    int y0 = yg << 2;
    int c0 = xg << 2;
    const float* p = x + (size_t)img * HH * WW;

    // Halo float4 loads, address-clamped inside the row (no OOB), value-masked
    // at image borders. Wave-wise these are coalesced and hit the same cache
    // lines as the neighbors' main loads — dense L1 transactions, no gathers.
    const bool hasL = (xg > 0);
    const bool hasR = (xg < XG - 1);
    const int  offL = hasL ? -4 : 0;
    const int  offR = hasR ?  4 : 0;

    // 6 rows (y0-1 .. y0+4) x 6 cols (c0-1 .. c0+4), zero-padded at borders
    float c[6][6];
#pragma unroll
    for (int dr = 0; dr < 6; ++dr) {
        int r = y0 + dr - 1;
        float4 m = make_float4(0.f, 0.f, 0.f, 0.f);
        float l = 0.f, rr = 0.f;
        if (r >= 0 && r < HH) {          // wave-uniform (yg constant per wave)
            const float* row = p + (size_t)r * WW + c0;
            m = *reinterpret_cast<const float4*>(row);
            float4 Lf = *reinterpret_cast<const float4*>(row + offL);
            float4 Rf = *reinterpret_cast<const float4*>(row + offR);
            l  = hasL ? Lf.w : 0.f;
            rr = hasR ? Rf.x : 0.f;
        }
        c[dr][0] = l;
        c[dr][1] = m.x; c[dr][2] = m.y; c[dr][3] = m.z; c[dr][4] = m.w;
        c[dr][5] = rr;
    }

    float* outp = out + (size_t)img * HH * WW + (size_t)y0 * WW + c0;
#pragma unroll
    for (int t = 0; t < 4; ++t) {
        // sort each of the 6 columns of the 3-row window (t..t+2)
        float lo[6], mi[6], hi[6];
#pragma unroll
        for (int j = 0; j < 6; ++j) {
            float a = c[t][j], b = c[t + 1][j], d = c[t + 2][j];
            lo[j] = fminf(fminf(a, b), d);
            hi[j] = fmaxf(fmaxf(a, b), d);
            mi[j] = __builtin_amdgcn_fmed3f(a, b, d);
        }
        // Smith: median9 = med3(max3(lows), med3(mids), min3(highs))
        float4 o;
        float* op = &o.x;
#pragma unroll
        for (int j = 0; j < 4; ++j) {
            float mx = fmaxf(fmaxf(lo[j], lo[j + 1]), lo[j + 2]);
            float md = __builtin_amdgcn_fmed3f(mi[j], mi[j + 1], mi[j + 2]);
            float mn = fminf(fminf(hi[j], hi[j + 1]), hi[j + 2]);
            op[j] = __builtin_amdgcn_fmed3f(mx, md, mn);
        }
        *reinterpret_cast<float4*>(outp + (size_t)t * WW) = o;
    }
}

extern "C" void kernel_launch(void* const* d_in, const int* in_sizes, int n_in,
                              void* d_out, int out_size, void* d_ws, size_t ws_size,
                              hipStream_t stream) {
    const float* x = (const float*)d_in[0];
    float* out = (float*)d_out;
    int nimg = in_sizes[0] / (HH * WW);          // 16 * 3 = 48
    int total_threads = nimg * YG * XG;          // one thread per 4x4 output tile
    int block = 256;
    int grid = (total_threads + block - 1) / block;
    median3_kernel<<<grid, block, 0, stream>>>(x, out, nimg);
}

// Round 5
// 21.408 us; speedup vs baseline: 1.1570x; 1.1522x over previous
//
#include <hip/hip_runtime.h>

#define HH 512
#define WW 512
#define XG 128   // col groups  (WW/4)
#define YG 128   // row groups  (HH/4)
#define NXCD 8

__global__ __launch_bounds__(256) void median3_kernel(const float* __restrict__ x,
                                                      float* __restrict__ out,
                                                      int nimg, int cpx) {
    // XCD-aware swizzle: consecutive hardware blocks round-robin across the 8
    // XCD L2s; remap so each XCD processes a CONTIGUOUS chunk of tiles, making
    // the vertical halo rows (shared between adjacent tile-rows) L2 hits
    // instead of second HBM fetches.  grid % 8 == 0 (3072 = 8*384).
    int bid = blockIdx.x;
    int swz = (bid % NXCD) * cpx + bid / NXCD;
    int tid = swz * blockDim.x + threadIdx.x;

    int xg  = tid & (XG - 1);           // 4-col group
    int yg  = (tid >> 7) & (YG - 1);    // 4-row group
    int img = tid >> 14;
    if (img >= nimg) return;

    int y0 = yg << 2;
    int c0 = xg << 2;
    const float* p = x + (size_t)img * HH * WW;

    // 6 rows (y0-1 .. y0+4) x 6 cols (c0-1 .. c0+4), zero-padded at borders
    float c[6][6];
#pragma unroll
    for (int dr = 0; dr < 6; ++dr) {
        int r = y0 + dr - 1;
        float4 m = make_float4(0.f, 0.f, 0.f, 0.f);
        float l = 0.f, rr = 0.f;
        if (r >= 0 && r < HH) {          // wave-uniform (yg constant per wave)
            const float* row = p + (size_t)r * WW + c0;
            m = *reinterpret_cast<const float4*>(row);
            if (xg > 0)      l  = row[-1];
            if (xg < XG - 1) rr = row[4];
        }
        c[dr][0] = l;
        c[dr][1] = m.x; c[dr][2] = m.y; c[dr][3] = m.z; c[dr][4] = m.w;
        c[dr][5] = rr;
    }

    float* outp = out + (size_t)img * HH * WW + (size_t)y0 * WW + c0;
#pragma unroll
    for (int t = 0; t < 4; ++t) {
        // sort each of the 6 columns of the 3-row window (t..t+2)
        float lo[6], mi[6], hi[6];
#pragma unroll
        for (int j = 0; j < 6; ++j) {
            float a = c[t][j], b = c[t + 1][j], d = c[t + 2][j];
            lo[j] = fminf(fminf(a, b), d);
            hi[j] = fmaxf(fmaxf(a, b), d);
            mi[j] = __builtin_amdgcn_fmed3f(a, b, d);
        }
        // Smith: median9 = med3(max3(lows), med3(mids), min3(highs))
        float4 o;
        float* op = &o.x;
#pragma unroll
        for (int j = 0; j < 4; ++j) {
            float mx = fmaxf(fmaxf(lo[j], lo[j + 1]), lo[j + 2]);
            float md = __builtin_amdgcn_fmed3f(mi[j], mi[j + 1], mi[j + 2]);
            float mn = fminf(fminf(hi[j], hi[j + 1]), hi[j + 2]);
            op[j] = __builtin_amdgcn_fmed3f(mx, md, mn);
        }
        *reinterpret_cast<float4*>(outp + (size_t)t * WW) = o;
    }
}

extern "C" void kernel_launch(void* const* d_in, const int* in_sizes, int n_in,
                              void* d_out, int out_size, void* d_ws, size_t ws_size,
                              hipStream_t stream) {
    const float* x = (const float*)d_in[0];
    float* out = (float*)d_out;
    int nimg = in_sizes[0] / (HH * WW);          // 16 * 3 = 48
    int total_threads = nimg * YG * XG;          // one thread per 4x4 output tile
    int block = 256;
    int grid = (total_threads + block - 1) / block;   // 3072, divisible by 8
    int cpx = grid / NXCD;
    median3_kernel<<<grid, block, 0, stream>>>(x, out, nimg, cpx);
}